// Round 14
// baseline (981.118 us; speedup 1.0000x reference)
//
#include <hip/hip_runtime.h>
#include <math.h>

#define D_MODEL 384
#define D_INNER 768
#define D_STATE 16
#define DT_RANK 24
#define NTOK    2048
#define XDIM    56    // DT_RANK + 2*D_STATE
#define CHUNK   32
#define NCHUNK  (NTOK / CHUNK)   // 64

typedef __attribute__((ext_vector_type(8))) short bf16x8;
typedef __attribute__((ext_vector_type(4))) float f32x4;

// ---------- ordering maps: sequence position p -> canonical token (l*256+h*16+w)
__device__ __forceinline__ int tok_of(int order, int p) {
    int q = (order & 1) ? (NTOK - 1 - p) : p;
    int grp = order >> 1;          // 0: HWL, 1: LWH, 2: LHW (canonical)
    int l, h, w;
    if (grp == 0)      { h = q >> 7;  w = (q >> 3) & 15; l = q & 7;  }
    else if (grp == 1) { l = q >> 8;  w = (q >> 4) & 15; h = q & 15; }
    else               { return q; }
    return l * 256 + h * 16 + w;
}

__device__ __forceinline__ float sigmoidf_(float x) { return 1.f / (1.f + expf(-x)); }
__device__ __forceinline__ float softplusf_(float x) { return (x > 20.f) ? x : log1pf(expf(x)); }

// split fp32 -> bf16 hi (truncate) + bf16 lo (residual, truncate)
__device__ __forceinline__ void bf16split_(float a, unsigned short& hb, unsigned short& lb) {
    unsigned int ab = __float_as_uint(a);
    hb = (unsigned short)(ab >> 16);
    float hf = __uint_as_float(ab & 0xFFFF0000u);
    lb = (unsigned short)(__float_as_uint(a - hf) >> 16);
}

// ---------- pre-split a float array into bf16 hi/lo (float4-vectorized)
__global__ __launch_bounds__(256) void presplit_k(
    const float* __restrict__ A, unsigned short* __restrict__ H,
    unsigned short* __restrict__ L, int n4)
{
    const int i = blockIdx.x * 256 + threadIdx.x;
    if (i >= n4) return;
    const float4 v = ((const float4*)A)[i];
    ushort4 h, l;
    bf16split_(v.x, h.x, l.x);
    bf16split_(v.y, h.y, l.y);
    bf16split_(v.z, h.z, l.z);
    bf16split_(v.w, h.w, l.w);
    ((ushort4*)H)[i] = h;
    ((ushort4*)L)[i] = l;
}

// ---------- RMSNorm with gather; emits bf16 hi/lo directly
__global__ __launch_bounds__(128) void rmsnorm_gather_k(
    const float* __restrict__ R, const float* __restrict__ nw,
    unsigned short* __restrict__ Xnh, unsigned short* __restrict__ Xnl, int order)
{
    const int p   = blockIdx.x;
    const int tok = tok_of(order, p);
    const float* src = R + tok * D_MODEL;
    const int tid = threadIdx.x;
    float v0 = src[tid], v1 = src[tid + 128], v2 = src[tid + 256];
    float ss = v0 * v0 + v1 * v1 + v2 * v2;
#pragma unroll
    for (int off = 32; off > 0; off >>= 1) ss += __shfl_xor(ss, off);
    __shared__ float tot[2];
    if ((tid & 63) == 0) tot[tid >> 6] = ss;
    __syncthreads();
    const float rs = rsqrtf((tot[0] + tot[1]) * (1.f / D_MODEL) + 1e-5f);
    unsigned short h, l;
    bf16split_(v0 * rs * nw[tid], h, l);
    Xnh[p * D_MODEL + tid] = h;       Xnl[p * D_MODEL + tid] = l;
    bf16split_(v1 * rs * nw[tid + 128], h, l);
    Xnh[p * D_MODEL + tid + 128] = h; Xnl[p * D_MODEL + tid + 128] = l;
    bf16split_(v2 * rs * nw[tid + 256], h, l);
    Xnh[p * D_MODEL + tid + 256] = h; Xnl[p * D_MODEL + tid + 256] = l;
}

// ---------- in_proj via bf16x3 MFMA (pre-split operands): C = Xn[2048x384] * W[1536x384]^T
// n<768  -> XP[t*768+n] = c ; n>=768 -> G[t*768+(n-768)] = silu(c)
__global__ __launch_bounds__(256, 3) void inproj_mfma_k(
    const unsigned short* __restrict__ Ahg, const unsigned short* __restrict__ Alg,
    const unsigned short* __restrict__ WH, const unsigned short* __restrict__ WL,
    float* __restrict__ XP, float* __restrict__ G)
{
    __shared__ __align__(16) short Ah[4 * 64 * 8];
    __shared__ __align__(16) short Al[4 * 64 * 8];
    __shared__ __align__(16) short Bh[4 * 64 * 8];
    __shared__ __align__(16) short Bl[4 * 64 * 8];

    const int tid = threadIdx.x;
    const int m0 = blockIdx.y * 64;
    const int n0 = blockIdx.x * 64;
    const int w  = tid >> 6;
    const int l  = tid & 63;
    const int lr = l & 15;
    const int kg = l >> 4;
    const int srow = tid >> 2;      // 0..63
    const int skq  = tid & 3;       // k-quarter

    f32x4 acc[4];
#pragma unroll
    for (int r = 0; r < 4; ++r) acc[r] = (f32x4){0.f, 0.f, 0.f, 0.f};

    for (int k0 = 0; k0 < D_MODEL; k0 += 32) {
        const int aoff = (m0 + srow) * D_MODEL + k0 + skq * 8;
        const int woff = (n0 + srow) * D_MODEL + k0 + skq * 8;
        const int soff = (skq * 64 + srow) * 8;
        *(bf16x8*)&Ah[soff] = *(const bf16x8*)&Ahg[aoff];
        *(bf16x8*)&Al[soff] = *(const bf16x8*)&Alg[aoff];
        *(bf16x8*)&Bh[soff] = *(const bf16x8*)&WH[woff];
        *(bf16x8*)&Bl[soff] = *(const bf16x8*)&WL[woff];
        __syncthreads();

        const bf16x8 bh = *(const bf16x8*)&Bh[(kg * 64 + w * 16 + lr) * 8];
        const bf16x8 bl = *(const bf16x8*)&Bl[(kg * 64 + w * 16 + lr) * 8];
#pragma unroll
        for (int r = 0; r < 4; ++r) {
            const bf16x8 ah = *(const bf16x8*)&Ah[(kg * 64 + r * 16 + lr) * 8];
            const bf16x8 al = *(const bf16x8*)&Al[(kg * 64 + r * 16 + lr) * 8];
            acc[r] = __builtin_amdgcn_mfma_f32_16x16x32_bf16(ah, bh, acc[r], 0, 0, 0);
            acc[r] = __builtin_amdgcn_mfma_f32_16x16x32_bf16(ah, bl, acc[r], 0, 0, 0);
            acc[r] = __builtin_amdgcn_mfma_f32_16x16x32_bf16(al, bh, acc[r], 0, 0, 0);
        }
        __syncthreads();
    }

    const int n = n0 + w * 16 + lr;
    if (n0 < D_INNER) {
#pragma unroll
        for (int r = 0; r < 4; ++r)
#pragma unroll
            for (int i = 0; i < 4; ++i) {
                const int t = m0 + r * 16 + kg * 4 + i;
                XP[t * D_INNER + n] = acc[r][i];
            }
    } else {
        const int n2 = n - D_INNER;
#pragma unroll
        for (int r = 0; r < 4; ++r)
#pragma unroll
            for (int i = 0; i < 4; ++i) {
                const int t = m0 + r * 16 + kg * 4 + i;
                const float c = acc[r][i];
                G[t * D_INNER + n2] = c * sigmoidf_(c);
            }
    }
}

// ---------- out_proj via bf16x3 MFMA, split-K z=2: PO[z][t][col] = YG * W^T slice
__global__ __launch_bounds__(256, 3) void outproj_mfma_k(
    const float* __restrict__ YG, const unsigned short* __restrict__ WH,
    const unsigned short* __restrict__ WL, float* __restrict__ PO)
{
    __shared__ __align__(16) short Ah[4 * 64 * 8];
    __shared__ __align__(16) short Al[4 * 64 * 8];
    __shared__ __align__(16) short Bh[4 * 64 * 8];
    __shared__ __align__(16) short Bl[4 * 64 * 8];

    const int tid = threadIdx.x;
    const int m0 = blockIdx.y * 64;
    const int n0 = blockIdx.x * 64;
    const int kb = blockIdx.z * 384;
    const int w  = tid >> 6;
    const int l  = tid & 63;
    const int lr = l & 15;
    const int kg = l >> 4;
    const int srow = tid >> 2;
    const int skq  = tid & 3;

    f32x4 acc[4];
#pragma unroll
    for (int r = 0; r < 4; ++r) acc[r] = (f32x4){0.f, 0.f, 0.f, 0.f};

    for (int k0 = 0; k0 < 384; k0 += 32) {
        const float* ap = YG + (m0 + srow) * D_INNER + kb + k0 + skq * 8;
        const float4 a0 = *(const float4*)ap;
        const float4 a1 = *(const float4*)(ap + 4);
        const float av[8] = {a0.x, a0.y, a0.z, a0.w, a1.x, a1.y, a1.z, a1.w};
        union { bf16x8 v; unsigned short u[8]; } hu, lu;
#pragma unroll
        for (int j = 0; j < 8; ++j) bf16split_(av[j], hu.u[j], lu.u[j]);
        const int soff = (skq * 64 + srow) * 8;
        *(bf16x8*)&Ah[soff] = hu.v;
        *(bf16x8*)&Al[soff] = lu.v;
        const int woff = (n0 + srow) * D_INNER + kb + k0 + skq * 8;
        *(bf16x8*)&Bh[soff] = *(const bf16x8*)&WH[woff];
        *(bf16x8*)&Bl[soff] = *(const bf16x8*)&WL[woff];
        __syncthreads();

        const bf16x8 bh = *(const bf16x8*)&Bh[(kg * 64 + w * 16 + lr) * 8];
        const bf16x8 bl = *(const bf16x8*)&Bl[(kg * 64 + w * 16 + lr) * 8];
#pragma unroll
        for (int r = 0; r < 4; ++r) {
            const bf16x8 ah = *(const bf16x8*)&Ah[(kg * 64 + r * 16 + lr) * 8];
            const bf16x8 al = *(const bf16x8*)&Al[(kg * 64 + r * 16 + lr) * 8];
            acc[r] = __builtin_amdgcn_mfma_f32_16x16x32_bf16(ah, bh, acc[r], 0, 0, 0);
            acc[r] = __builtin_amdgcn_mfma_f32_16x16x32_bf16(ah, bl, acc[r], 0, 0, 0);
            acc[r] = __builtin_amdgcn_mfma_f32_16x16x32_bf16(al, bh, acc[r], 0, 0, 0);
        }
        __syncthreads();
    }

    float* Cz = PO + (size_t)blockIdx.z * NTOK * D_MODEL;
    const int n = n0 + w * 16 + lr;
#pragma unroll
    for (int r = 0; r < 4; ++r)
#pragma unroll
        for (int i = 0; i < 4; ++i) {
            const int t = m0 + r * 16 + kg * 4 + i;
            Cz[t * D_MODEL + n] = acc[r][i];
        }
}

// ---------- generic tiled fp32 GEMM (x_proj / dt_proj)
// MODE 1: row store + softplus(acc+bias[col]): C[row*N+col].
// MODE 3: transposed store C[z*N*NTOK + col*NTOK+row].
template<int MODE, bool TRANSA>
__global__ __launch_bounds__(256, 2) void gemm_k(
    const float* __restrict__ A, int lda,
    const float* __restrict__ W,
    float* __restrict__ C,
    int M, int N, int K,
    const float* __restrict__ bias,
    float* __restrict__ C2,
    int kspan)
{
    __shared__ float As[16][68];
    __shared__ float Ws[16][68];
    const int tid = threadIdx.x;
    const int m0 = blockIdx.y * 64;
    const int n0 = blockIdx.x * 64;
    const int tx = tid & 15, ty = tid >> 4;
    const int lrow = tid >> 2;
    const int lk   = (tid & 3) << 2;
    const int kb   = blockIdx.z * kspan;
    const int ke   = (kb + kspan < K) ? (kb + kspan) : K;
    float acc[4][4] = {{0.f}};

    for (int k0 = kb; k0 < ke; k0 += 16) {
        if (TRANSA) {
            const int kk = k0 + (tid & 15);
            const int mq = tid >> 4;
            float4 v = make_float4(0.f, 0.f, 0.f, 0.f);
            if (kk < K) v = *(const float4*)&A[kk * lda + m0 + mq * 4];
            *(float4*)&As[tid & 15][mq * 4] = v;
        } else {
            const int m = m0 + lrow;
            const float* src = A + m * lda + (k0 + lk);
            float4 v = make_float4(0.f, 0.f, 0.f, 0.f);
            if (k0 + lk + 3 < K) v = *(const float4*)src;
            else {
                if (k0 + lk + 0 < K) v.x = src[0];
                if (k0 + lk + 1 < K) v.y = src[1];
                if (k0 + lk + 2 < K) v.z = src[2];
            }
            As[lk + 0][lrow] = v.x; As[lk + 1][lrow] = v.y;
            As[lk + 2][lrow] = v.z; As[lk + 3][lrow] = v.w;
        }
        {
            const int n = n0 + lrow;
            float4 u = make_float4(0.f, 0.f, 0.f, 0.f);
            if (n < N) {
                const float* srcw = W + n * K + (k0 + lk);
                if (k0 + lk + 3 < K) u = *(const float4*)srcw;
                else {
                    if (k0 + lk + 0 < K) u.x = srcw[0];
                    if (k0 + lk + 1 < K) u.y = srcw[1];
                    if (k0 + lk + 2 < K) u.z = srcw[2];
                }
            }
            Ws[lk + 0][lrow] = u.x; Ws[lk + 1][lrow] = u.y;
            Ws[lk + 2][lrow] = u.z; Ws[lk + 3][lrow] = u.w;
        }
        __syncthreads();
#pragma unroll
        for (int k = 0; k < 16; ++k) {
            float4 a4 = *(const float4*)&As[k][ty * 4];
            float4 w4 = *(const float4*)&Ws[k][tx * 4];
            float ar[4] = {a4.x, a4.y, a4.z, a4.w};
            float wr[4] = {w4.x, w4.y, w4.z, w4.w};
#pragma unroll
            for (int i = 0; i < 4; ++i)
#pragma unroll
                for (int j = 0; j < 4; ++j)
                    acc[i][j] = fmaf(ar[i], wr[j], acc[i][j]);
        }
        __syncthreads();
    }

    const int row0 = m0 + ty * 4;
    const int col0 = n0 + tx * 4;
    if (MODE == 1) {
        const float4 bv = *(const float4*)&bias[col0];
#pragma unroll
        for (int i = 0; i < 4; ++i) {
            float4 v = make_float4(softplusf_(acc[i][0] + bv.x), softplusf_(acc[i][1] + bv.y),
                                   softplusf_(acc[i][2] + bv.z), softplusf_(acc[i][3] + bv.w));
            *(float4*)&C[(row0 + i) * N + col0] = v;
        }
    } else if (MODE == 3) {
        float* Cz = C + (size_t)blockIdx.z * N * NTOK;
#pragma unroll
        for (int j = 0; j < 4; ++j) {
            const int col = col0 + j;
            if (col < N) {
                float4 v = make_float4(acc[0][j], acc[1][j], acc[2][j], acc[3][j]);
                *(float4*)&Cz[col * NTOK + row0] = v;
            }
        }
    }
}

// ---------- reduce split-K partials PX[8][56][2048] -> XDT[e][t]
__global__ __launch_bounds__(256) void reduce_px_k(
    const float* __restrict__ PX, float* __restrict__ XDT)
{
    const int i4 = blockIdx.x * 256 + threadIdx.x;
    float4 s = ((const float4*)PX)[i4];
#pragma unroll
    for (int z = 1; z < 8; ++z) {
        float4 v = ((const float4*)PX)[z * (XDIM * NTOK / 4) + i4];
        s.x += v.x; s.y += v.y; s.z += v.z; s.w += v.w;
    }
    ((float4*)XDT)[i4] = s;
}

// ---------- reduce split-K partials PO[2][2048][384] + scatter-accumulate into R
__global__ __launch_bounds__(384) void reduce_scatter_k(
    const float* __restrict__ PO, float* __restrict__ R, int order)
{
    const int m = blockIdx.x;
    const int col = threadIdx.x;
    float s = PO[m * D_MODEL + col] + PO[NTOK * D_MODEL + m * D_MODEL + col];
    const int tok = tok_of(order, m);
    R[tok * D_MODEL + col] += s;
}

// ---------- causal depthwise conv (k=4) + SiLU; XP[t][d] -> XC[t][d] (row-major)
__global__ __launch_bounds__(256) void conv_silu_k(
    const float* __restrict__ XP, const float* __restrict__ cw,
    const float* __restrict__ cb, float* __restrict__ XC)
{
    const int d = blockIdx.x * 256 + threadIdx.x;   // grid.x = 3
    const int t = blockIdx.y;
    const float4 w4 = *(const float4*)(cw + d * 4);
    float acc = cb[d];
    if (t >= 3) acc = fmaf(w4.x, XP[(t - 3) * D_INNER + d], acc);
    if (t >= 2) acc = fmaf(w4.y, XP[(t - 2) * D_INNER + d], acc);
    if (t >= 1) acc = fmaf(w4.z, XP[(t - 1) * D_INNER + d], acc);
    acc = fmaf(w4.w, XP[t * D_INNER + d], acc);
    XC[t * D_INNER + d] = acc * sigmoidf_(acc);
}

// ---------- scan phase 1: thread = one d-channel, all 16 states in registers
__global__ __launch_bounds__(256) void scan_phase1_k(
    const float* __restrict__ XC, const float* __restrict__ DT,
    const float* __restrict__ XDT, const float* __restrict__ A_log,
    float* __restrict__ Aprod, float* __restrict__ Hpart)
{
    __shared__ float Bs[CHUNK][D_STATE];
    const int d = blockIdx.x * 256 + threadIdx.x;   // grid.x = 3
    const int chunk = blockIdx.y;
    const int t0 = chunk * CHUNK;
    for (int i = threadIdx.x; i < CHUNK * D_STATE; i += 256) {
        const int tt = i >> 4, s = i & 15;
        Bs[tt][s] = XDT[(DT_RANK + s) * NTOK + t0 + tt];
    }
    __syncthreads();
    float An[D_STATE], h[D_STATE], ap[D_STATE];
#pragma unroll
    for (int s = 0; s < D_STATE; ++s) {
        An[s] = -expf(A_log[d * D_STATE + s]);
        h[s] = 0.f; ap[s] = 1.f;
    }
#pragma unroll 4
    for (int tt = 0; tt < CHUNK; ++tt) {
        const float dt = DT[(t0 + tt) * D_INNER + d];
        const float u  = XC[(t0 + tt) * D_INNER + d];
        const float dtu = dt * u;
#pragma unroll
        for (int s = 0; s < D_STATE; ++s) {
            const float a = expf(dt * An[s]);
            h[s] = fmaf(a, h[s], dtu * Bs[tt][s]);
            ap[s] *= a;
        }
    }
    float* apd = Aprod + (chunk * D_INNER + d) * D_STATE;
    float* hpd = Hpart + (chunk * D_INNER + d) * D_STATE;
#pragma unroll
    for (int s = 0; s < D_STATE; ++s) { apd[s] = ap[s]; hpd[s] = h[s]; }
}

// ---------- phase 2 (unchanged layout: [chunk][d*16+s])
__global__ __launch_bounds__(256) void scan_phase2_k(
    const float* __restrict__ Aprod, const float* __restrict__ Hpart,
    float* __restrict__ Hinit)
{
    const int tid = blockIdx.x * 256 + threadIdx.x;
    float h = 0.f;
#pragma unroll 8
    for (int c = 0; c < NCHUNK; ++c) {
        const int idx = c * (D_INNER * D_STATE) + tid;
        Hinit[idx] = h;
        h = fmaf(Aprod[idx], h, Hpart[idx]);
    }
}

// ---------- scan phase 3: thread = one d; in-register y-reduction; fused u*D + gate
__global__ __launch_bounds__(256) void scan_phase3_k(
    const float* __restrict__ XC, const float* __restrict__ DT,
    const float* __restrict__ XDT, const float* __restrict__ G,
    const float* __restrict__ A_log, const float* __restrict__ Dp,
    const float* __restrict__ Hinit, float* __restrict__ YG)
{
    __shared__ float Bs[CHUNK][D_STATE];
    __shared__ float Cs[CHUNK][D_STATE];
    const int d = blockIdx.x * 256 + threadIdx.x;   // grid.x = 3
    const int chunk = blockIdx.y;
    const int t0 = chunk * CHUNK;
    for (int i = threadIdx.x; i < CHUNK * D_STATE; i += 256) {
        const int tt = i >> 4, s = i & 15;
        Bs[tt][s] = XDT[(DT_RANK + s) * NTOK + t0 + tt];
        Cs[tt][s] = XDT[(DT_RANK + D_STATE + s) * NTOK + t0 + tt];
    }
    __syncthreads();
    const float Dv = Dp[d];
    float An[D_STATE], h[D_STATE];
    const float* hin = Hinit + (chunk * D_INNER + d) * D_STATE;
#pragma unroll
    for (int s = 0; s < D_STATE; ++s) {
        An[s] = -expf(A_log[d * D_STATE + s]);
        h[s] = hin[s];
    }
#pragma unroll 4
    for (int tt = 0; tt < CHUNK; ++tt) {
        const float dt = DT[(t0 + tt) * D_INNER + d];
        const float u  = XC[(t0 + tt) * D_INNER + d];
        const float g  = G[(t0 + tt) * D_INNER + d];
        const float dtu = dt * u;
        float y = 0.f;
#pragma unroll
        for (int s = 0; s < D_STATE; ++s) {
            const float a = expf(dt * An[s]);
            h[s] = fmaf(a, h[s], dtu * Bs[tt][s]);
            y = fmaf(h[s], Cs[tt][s], y);
        }
        YG[(t0 + tt) * D_INNER + d] = (y + u * Dv) * g;
    }
}

extern "C" void kernel_launch(void* const* d_in, const int* in_sizes, int n_in,
                              void* d_out, int out_size, void* d_ws, size_t ws_size,
                              hipStream_t stream)
{
    const float* x        = (const float*)d_in[0];
    const float* norm_w   = (const float*)d_in[1];
    const float* in_proj  = (const float*)d_in[2];
    const float* conv_w   = (const float*)d_in[3];
    const float* conv_b   = (const float*)d_in[4];
    const float* x_proj   = (const float*)d_in[5];
    const float* dt_proj  = (const float*)d_in[6];
    const float* dt_b     = (const float*)d_in[7];
    const float* A_log    = (const float*)d_in[8];
    const float* D_param  = (const float*)d_in[9];
    const float* out_proj = (const float*)d_in[10];

    float* ws = (float*)d_ws;
    float* R     = ws;                     // 786432
    float* XP    = R   + 786432;           // 1572864 (alias: PX 917504; Hinit 786432)
    float* XnHL  = XP  + 1572864;          // 786432  (Xnh/Xnl; alias: Aprod)
    float* G     = XnHL + 786432;          // 1572864 (alias: PO after phase3)
    float* XC    = G   + 1572864;          // 1572864
    float* XDT   = XC  + 1572864;          // 114688
    float* DT    = XDT + 114688;           // 1572864
    float* YG    = DT  + 1572864;          // 1572864 (alias: Hpart)
    float* WS1   = YG  + 1572864;          // weight splits below
    unsigned short* Xnh  = (unsigned short*)XnHL;
    unsigned short* Xnl  = Xnh + 786432;
    unsigned short* WinH = (unsigned short*)WS1;                 // 6*1536*384
    unsigned short* WinL = WinH + 6 * 1536 * 384;
    unsigned short* WoutH = WinL + 6 * 1536 * 384;               // 6*384*768
    unsigned short* WoutL = WoutH + 6 * 384 * 768;
    float* Aprod = XnHL;
    float* Hpart = YG;
    float* Hinit = XP;
    float* PX    = XP;
    float* PO    = G;

    hipMemcpyAsync(R, x, (size_t)786432 * sizeof(float), hipMemcpyDeviceToDevice, stream);

    // pre-split weights (once per launch, identical work every call)
    presplit_k<<<(6 * 1536 * 384 / 4 + 255) / 256, 256, 0, stream>>>(
        in_proj, WinH, WinL, 6 * 1536 * 384 / 4);
    presplit_k<<<(6 * 384 * 768 / 4 + 255) / 256, 256, 0, stream>>>(
        out_proj, WoutH, WoutL, 6 * 384 * 768 / 4);

    for (int b = 0; b < 6; ++b) {
        rmsnorm_gather_k<<<NTOK, 128, 0, stream>>>(R, norm_w + b * D_MODEL, Xnh, Xnl, b);

        inproj_mfma_k<<<dim3(24, 32), 256, 0, stream>>>(
            Xnh, Xnl, WinH + (size_t)b * 1536 * 384, WinL + (size_t)b * 1536 * 384, XP, G);

        conv_silu_k<<<dim3(3, NTOK), 256, 0, stream>>>(
            XP, conv_w + b * D_INNER * 4, conv_b + b * D_INNER, XC);

        // x_proj split-K: XC(2048x768 row-major) x W(56x768)^T -> PX[z][e][t]
        gemm_k<3, false><<<dim3(1, 32, 8), 256, 0, stream>>>(
            XC, D_INNER, x_proj + (size_t)b * XDIM * D_INNER, PX,
            NTOK, XDIM, D_INNER, nullptr, nullptr, 96);

        reduce_px_k<<<112, 256, 0, stream>>>(PX, XDT);

        // dt_proj: (XDT rows 0..23)^T x W(768x24)^T -> DT[t][d] softplus+bias
        gemm_k<1, true><<<dim3(12, 32, 1), 256, 0, stream>>>(
            XDT, NTOK, dt_proj + (size_t)b * D_INNER * DT_RANK, DT,
            NTOK, D_INNER, DT_RANK, dt_b + b * D_INNER, nullptr, DT_RANK);

        scan_phase1_k<<<dim3(3, NCHUNK), 256, 0, stream>>>(
            XC, DT, XDT, A_log + (size_t)b * D_INNER * D_STATE, Aprod, Hpart);

        scan_phase2_k<<<48, 256, 0, stream>>>(Aprod, Hpart, Hinit);

        scan_phase3_k<<<dim3(3, NCHUNK), 256, 0, stream>>>(
            XC, DT, XDT, G, A_log + (size_t)b * D_INNER * D_STATE,
            D_param + b * D_INNER, Hinit, YG);

        outproj_mfma_k<<<dim3(6, 32, 2), 256, 0, stream>>>(
            YG, WoutH + (size_t)b * 384 * 768, WoutL + (size_t)b * 384 * 768, PO);

        reduce_scatter_k<<<NTOK, 384, 0, stream>>>(PO, R, b);
    }

    hipMemcpyAsync(d_out, R, (size_t)786432 * sizeof(float), hipMemcpyDeviceToDevice, stream);
}

// Round 15
// 853.365 us; speedup vs baseline: 1.1497x; 1.1497x over previous
//
#include <hip/hip_runtime.h>
#include <math.h>

#define D_MODEL 384
#define D_INNER 768
#define D_STATE 16
#define DT_RANK 24
#define NTOK    2048
#define XDIM    56    // DT_RANK + 2*D_STATE
#define CHUNK   8
#define NCHUNK  (NTOK / CHUNK)   // 256

typedef __attribute__((ext_vector_type(8))) short bf16x8;
typedef __attribute__((ext_vector_type(4))) float f32x4;

// ---------- ordering maps: sequence position p -> canonical token (l*256+h*16+w)
__device__ __forceinline__ int tok_of(int order, int p) {
    int q = (order & 1) ? (NTOK - 1 - p) : p;
    int grp = order >> 1;          // 0: HWL, 1: LWH, 2: LHW (canonical)
    int l, h, w;
    if (grp == 0)      { h = q >> 7;  w = (q >> 3) & 15; l = q & 7;  }
    else if (grp == 1) { l = q >> 8;  w = (q >> 4) & 15; h = q & 15; }
    else               { return q; }
    return l * 256 + h * 16 + w;
}

__device__ __forceinline__ float sigmoidf_(float x) { return 1.f / (1.f + expf(-x)); }
__device__ __forceinline__ float softplusf_(float x) { return (x > 20.f) ? x : log1pf(expf(x)); }

// split fp32 -> bf16 hi (truncate) + bf16 lo (residual, truncate)
__device__ __forceinline__ void bf16split_(float a, unsigned short& hb, unsigned short& lb) {
    unsigned int ab = __float_as_uint(a);
    hb = (unsigned short)(ab >> 16);
    float hf = __uint_as_float(ab & 0xFFFF0000u);
    lb = (unsigned short)(__float_as_uint(a - hf) >> 16);
}

// ---------- pre-split a float array into bf16 hi/lo (float4-vectorized)
__global__ __launch_bounds__(256) void presplit_k(
    const float* __restrict__ A, unsigned short* __restrict__ H,
    unsigned short* __restrict__ L, int n4)
{
    const int i = blockIdx.x * 256 + threadIdx.x;
    if (i >= n4) return;
    const float4 v = ((const float4*)A)[i];
    ushort4 h, l;
    bf16split_(v.x, h.x, l.x);
    bf16split_(v.y, h.y, l.y);
    bf16split_(v.z, h.z, l.z);
    bf16split_(v.w, h.w, l.w);
    ((ushort4*)H)[i] = h;
    ((ushort4*)L)[i] = l;
}

// ---------- RMSNorm with gather; emits bf16 hi/lo directly
__global__ __launch_bounds__(128) void rmsnorm_gather_k(
    const float* __restrict__ R, const float* __restrict__ nw,
    unsigned short* __restrict__ Xnh, unsigned short* __restrict__ Xnl, int order)
{
    const int p   = blockIdx.x;
    const int tok = tok_of(order, p);
    const float* src = R + tok * D_MODEL;
    const int tid = threadIdx.x;
    float v0 = src[tid], v1 = src[tid + 128], v2 = src[tid + 256];
    float ss = v0 * v0 + v1 * v1 + v2 * v2;
#pragma unroll
    for (int off = 32; off > 0; off >>= 1) ss += __shfl_xor(ss, off);
    __shared__ float tot[2];
    if ((tid & 63) == 0) tot[tid >> 6] = ss;
    __syncthreads();
    const float rs = rsqrtf((tot[0] + tot[1]) * (1.f / D_MODEL) + 1e-5f);
    unsigned short h, l;
    bf16split_(v0 * rs * nw[tid], h, l);
    Xnh[p * D_MODEL + tid] = h;       Xnl[p * D_MODEL + tid] = l;
    bf16split_(v1 * rs * nw[tid + 128], h, l);
    Xnh[p * D_MODEL + tid + 128] = h; Xnl[p * D_MODEL + tid + 128] = l;
    bf16split_(v2 * rs * nw[tid + 256], h, l);
    Xnh[p * D_MODEL + tid + 256] = h; Xnl[p * D_MODEL + tid + 256] = l;
}

// ---------- in_proj via bf16x3 MFMA (pre-split operands): C = Xn[2048x384] * W[1536x384]^T
// n<768  -> XP[t*768+n] = c ; n>=768 -> G[t*768+(n-768)] = silu(c)
__global__ __launch_bounds__(256, 3) void inproj_mfma_k(
    const unsigned short* __restrict__ Ahg, const unsigned short* __restrict__ Alg,
    const unsigned short* __restrict__ WH, const unsigned short* __restrict__ WL,
    float* __restrict__ XP, float* __restrict__ G)
{
    __shared__ __align__(16) short Ah[4 * 64 * 8];
    __shared__ __align__(16) short Al[4 * 64 * 8];
    __shared__ __align__(16) short Bh[4 * 64 * 8];
    __shared__ __align__(16) short Bl[4 * 64 * 8];

    const int tid = threadIdx.x;
    const int m0 = blockIdx.y * 64;
    const int n0 = blockIdx.x * 64;
    const int w  = tid >> 6;
    const int l  = tid & 63;
    const int lr = l & 15;
    const int kg = l >> 4;
    const int srow = tid >> 2;      // 0..63
    const int skq  = tid & 3;       // k-quarter

    f32x4 acc[4];
#pragma unroll
    for (int r = 0; r < 4; ++r) acc[r] = (f32x4){0.f, 0.f, 0.f, 0.f};

    for (int k0 = 0; k0 < D_MODEL; k0 += 32) {
        const int aoff = (m0 + srow) * D_MODEL + k0 + skq * 8;
        const int woff = (n0 + srow) * D_MODEL + k0 + skq * 8;
        const int soff = (skq * 64 + srow) * 8;
        *(bf16x8*)&Ah[soff] = *(const bf16x8*)&Ahg[aoff];
        *(bf16x8*)&Al[soff] = *(const bf16x8*)&Alg[aoff];
        *(bf16x8*)&Bh[soff] = *(const bf16x8*)&WH[woff];
        *(bf16x8*)&Bl[soff] = *(const bf16x8*)&WL[woff];
        __syncthreads();

        const bf16x8 bh = *(const bf16x8*)&Bh[(kg * 64 + w * 16 + lr) * 8];
        const bf16x8 bl = *(const bf16x8*)&Bl[(kg * 64 + w * 16 + lr) * 8];
#pragma unroll
        for (int r = 0; r < 4; ++r) {
            const bf16x8 ah = *(const bf16x8*)&Ah[(kg * 64 + r * 16 + lr) * 8];
            const bf16x8 al = *(const bf16x8*)&Al[(kg * 64 + r * 16 + lr) * 8];
            acc[r] = __builtin_amdgcn_mfma_f32_16x16x32_bf16(ah, bh, acc[r], 0, 0, 0);
            acc[r] = __builtin_amdgcn_mfma_f32_16x16x32_bf16(ah, bl, acc[r], 0, 0, 0);
            acc[r] = __builtin_amdgcn_mfma_f32_16x16x32_bf16(al, bh, acc[r], 0, 0, 0);
        }
        __syncthreads();
    }

    const int n = n0 + w * 16 + lr;
    if (n0 < D_INNER) {
#pragma unroll
        for (int r = 0; r < 4; ++r)
#pragma unroll
            for (int i = 0; i < 4; ++i) {
                const int t = m0 + r * 16 + kg * 4 + i;
                XP[t * D_INNER + n] = acc[r][i];
            }
    } else {
        const int n2 = n - D_INNER;
#pragma unroll
        for (int r = 0; r < 4; ++r)
#pragma unroll
            for (int i = 0; i < 4; ++i) {
                const int t = m0 + r * 16 + kg * 4 + i;
                const float c = acc[r][i];
                G[t * D_INNER + n2] = c * sigmoidf_(c);
            }
    }
}

// ---------- out_proj via bf16x3 MFMA, split-K z=2: PO[z][t][col] = YG * W^T slice
__global__ __launch_bounds__(256, 3) void outproj_mfma_k(
    const float* __restrict__ YG, const unsigned short* __restrict__ WH,
    const unsigned short* __restrict__ WL, float* __restrict__ PO)
{
    __shared__ __align__(16) short Ah[4 * 64 * 8];
    __shared__ __align__(16) short Al[4 * 64 * 8];
    __shared__ __align__(16) short Bh[4 * 64 * 8];
    __shared__ __align__(16) short Bl[4 * 64 * 8];

    const int tid = threadIdx.x;
    const int m0 = blockIdx.y * 64;
    const int n0 = blockIdx.x * 64;
    const int kb = blockIdx.z * 384;
    const int w  = tid >> 6;
    const int l  = tid & 63;
    const int lr = l & 15;
    const int kg = l >> 4;
    const int srow = tid >> 2;
    const int skq  = tid & 3;

    f32x4 acc[4];
#pragma unroll
    for (int r = 0; r < 4; ++r) acc[r] = (f32x4){0.f, 0.f, 0.f, 0.f};

    for (int k0 = 0; k0 < 384; k0 += 32) {
        const float* ap = YG + (m0 + srow) * D_INNER + kb + k0 + skq * 8;
        const float4 a0 = *(const float4*)ap;
        const float4 a1 = *(const float4*)(ap + 4);
        const float av[8] = {a0.x, a0.y, a0.z, a0.w, a1.x, a1.y, a1.z, a1.w};
        union { bf16x8 v; unsigned short u[8]; } hu, lu;
#pragma unroll
        for (int j = 0; j < 8; ++j) bf16split_(av[j], hu.u[j], lu.u[j]);
        const int soff = (skq * 64 + srow) * 8;
        *(bf16x8*)&Ah[soff] = hu.v;
        *(bf16x8*)&Al[soff] = lu.v;
        const int woff = (n0 + srow) * D_INNER + kb + k0 + skq * 8;
        *(bf16x8*)&Bh[soff] = *(const bf16x8*)&WH[woff];
        *(bf16x8*)&Bl[soff] = *(const bf16x8*)&WL[woff];
        __syncthreads();

        const bf16x8 bh = *(const bf16x8*)&Bh[(kg * 64 + w * 16 + lr) * 8];
        const bf16x8 bl = *(const bf16x8*)&Bl[(kg * 64 + w * 16 + lr) * 8];
#pragma unroll
        for (int r = 0; r < 4; ++r) {
            const bf16x8 ah = *(const bf16x8*)&Ah[(kg * 64 + r * 16 + lr) * 8];
            const bf16x8 al = *(const bf16x8*)&Al[(kg * 64 + r * 16 + lr) * 8];
            acc[r] = __builtin_amdgcn_mfma_f32_16x16x32_bf16(ah, bh, acc[r], 0, 0, 0);
            acc[r] = __builtin_amdgcn_mfma_f32_16x16x32_bf16(ah, bl, acc[r], 0, 0, 0);
            acc[r] = __builtin_amdgcn_mfma_f32_16x16x32_bf16(al, bh, acc[r], 0, 0, 0);
        }
        __syncthreads();
    }

    float* Cz = PO + (size_t)blockIdx.z * NTOK * D_MODEL;
    const int n = n0 + w * 16 + lr;
#pragma unroll
    for (int r = 0; r < 4; ++r)
#pragma unroll
        for (int i = 0; i < 4; ++i) {
            const int t = m0 + r * 16 + kg * 4 + i;
            Cz[t * D_MODEL + n] = acc[r][i];
        }
}

// ---------- generic tiled fp32 GEMM (x_proj / dt_proj)
// MODE 1: row store + softplus(acc+bias[col]): C[row*N+col].
// MODE 3: transposed store C[z*N*NTOK + col*NTOK+row].
template<int MODE, bool TRANSA>
__global__ __launch_bounds__(256, 2) void gemm_k(
    const float* __restrict__ A, int lda,
    const float* __restrict__ W,
    float* __restrict__ C,
    int M, int N, int K,
    const float* __restrict__ bias,
    float* __restrict__ C2,
    int kspan)
{
    __shared__ float As[16][68];
    __shared__ float Ws[16][68];
    const int tid = threadIdx.x;
    const int m0 = blockIdx.y * 64;
    const int n0 = blockIdx.x * 64;
    const int tx = tid & 15, ty = tid >> 4;
    const int lrow = tid >> 2;
    const int lk   = (tid & 3) << 2;
    const int kb   = blockIdx.z * kspan;
    const int ke   = (kb + kspan < K) ? (kb + kspan) : K;
    float acc[4][4] = {{0.f}};

    for (int k0 = kb; k0 < ke; k0 += 16) {
        if (TRANSA) {
            const int kk = k0 + (tid & 15);
            const int mq = tid >> 4;
            float4 v = make_float4(0.f, 0.f, 0.f, 0.f);
            if (kk < K) v = *(const float4*)&A[kk * lda + m0 + mq * 4];
            *(float4*)&As[tid & 15][mq * 4] = v;
        } else {
            const int m = m0 + lrow;
            const float* src = A + m * lda + (k0 + lk);
            float4 v = make_float4(0.f, 0.f, 0.f, 0.f);
            if (k0 + lk + 3 < K) v = *(const float4*)src;
            else {
                if (k0 + lk + 0 < K) v.x = src[0];
                if (k0 + lk + 1 < K) v.y = src[1];
                if (k0 + lk + 2 < K) v.z = src[2];
            }
            As[lk + 0][lrow] = v.x; As[lk + 1][lrow] = v.y;
            As[lk + 2][lrow] = v.z; As[lk + 3][lrow] = v.w;
        }
        {
            const int n = n0 + lrow;
            float4 u = make_float4(0.f, 0.f, 0.f, 0.f);
            if (n < N) {
                const float* srcw = W + n * K + (k0 + lk);
                if (k0 + lk + 3 < K) u = *(const float4*)srcw;
                else {
                    if (k0 + lk + 0 < K) u.x = srcw[0];
                    if (k0 + lk + 1 < K) u.y = srcw[1];
                    if (k0 + lk + 2 < K) u.z = srcw[2];
                }
            }
            Ws[lk + 0][lrow] = u.x; Ws[lk + 1][lrow] = u.y;
            Ws[lk + 2][lrow] = u.z; Ws[lk + 3][lrow] = u.w;
        }
        __syncthreads();
#pragma unroll
        for (int k = 0; k < 16; ++k) {
            float4 a4 = *(const float4*)&As[k][ty * 4];
            float4 w4 = *(const float4*)&Ws[k][tx * 4];
            float ar[4] = {a4.x, a4.y, a4.z, a4.w};
            float wr[4] = {w4.x, w4.y, w4.z, w4.w};
#pragma unroll
            for (int i = 0; i < 4; ++i)
#pragma unroll
                for (int j = 0; j < 4; ++j)
                    acc[i][j] = fmaf(ar[i], wr[j], acc[i][j]);
        }
        __syncthreads();
    }

    const int row0 = m0 + ty * 4;
    const int col0 = n0 + tx * 4;
    if (MODE == 1) {
        const float4 bv = *(const float4*)&bias[col0];
#pragma unroll
        for (int i = 0; i < 4; ++i) {
            float4 v = make_float4(softplusf_(acc[i][0] + bv.x), softplusf_(acc[i][1] + bv.y),
                                   softplusf_(acc[i][2] + bv.z), softplusf_(acc[i][3] + bv.w));
            *(float4*)&C[(row0 + i) * N + col0] = v;
        }
    } else if (MODE == 3) {
        float* Cz = C + (size_t)blockIdx.z * N * NTOK;
#pragma unroll
        for (int j = 0; j < 4; ++j) {
            const int col = col0 + j;
            if (col < N) {
                float4 v = make_float4(acc[0][j], acc[1][j], acc[2][j], acc[3][j]);
                *(float4*)&Cz[col * NTOK + row0] = v;
            }
        }
    }
}

// ---------- reduce split-K partials PX[8][56][2048] -> XDT[e][t]
__global__ __launch_bounds__(256) void reduce_px_k(
    const float* __restrict__ PX, float* __restrict__ XDT)
{
    const int i4 = blockIdx.x * 256 + threadIdx.x;
    float4 s = ((const float4*)PX)[i4];
#pragma unroll
    for (int z = 1; z < 8; ++z) {
        float4 v = ((const float4*)PX)[z * (XDIM * NTOK / 4) + i4];
        s.x += v.x; s.y += v.y; s.z += v.z; s.w += v.w;
    }
    ((float4*)XDT)[i4] = s;
}

// ---------- reduce split-K partials PO[2][2048][384] + scatter-accumulate into R
__global__ __launch_bounds__(384) void reduce_scatter_k(
    const float* __restrict__ PO, float* __restrict__ R, int order)
{
    const int m = blockIdx.x;
    const int col = threadIdx.x;
    float s = PO[m * D_MODEL + col] + PO[NTOK * D_MODEL + m * D_MODEL + col];
    const int tok = tok_of(order, m);
    R[tok * D_MODEL + col] += s;
}

// ---------- causal depthwise conv (k=4) + SiLU; XP[t][d] -> XC[t][d] (row-major)
__global__ __launch_bounds__(256) void conv_silu_k(
    const float* __restrict__ XP, const float* __restrict__ cw,
    const float* __restrict__ cb, float* __restrict__ XC)
{
    const int d = blockIdx.x * 256 + threadIdx.x;   // grid.x = 3
    const int t = blockIdx.y;
    const float4 w4 = *(const float4*)(cw + d * 4);
    float acc = cb[d];
    if (t >= 3) acc = fmaf(w4.x, XP[(t - 3) * D_INNER + d], acc);
    if (t >= 2) acc = fmaf(w4.y, XP[(t - 2) * D_INNER + d], acc);
    if (t >= 1) acc = fmaf(w4.z, XP[(t - 1) * D_INNER + d], acc);
    acc = fmaf(w4.w, XP[t * D_INNER + d], acc);
    XC[t * D_INNER + d] = acc * sigmoidf_(acc);
}

// ---------- scan phase 1: thread = one d-channel, all 16 states in registers
__global__ __launch_bounds__(256) void scan_phase1_k(
    const float* __restrict__ XC, const float* __restrict__ DT,
    const float* __restrict__ XDT, const float* __restrict__ A_log,
    float* __restrict__ Aprod, float* __restrict__ Hpart)
{
    __shared__ float Bs[CHUNK][D_STATE];
    const int d = blockIdx.x * 256 + threadIdx.x;   // grid.x = 3
    const int chunk = blockIdx.y;
    const int t0 = chunk * CHUNK;
    if (threadIdx.x < CHUNK * D_STATE) {
        const int tt = threadIdx.x >> 4, s = threadIdx.x & 15;
        Bs[tt][s] = XDT[(DT_RANK + s) * NTOK + t0 + tt];
    }
    __syncthreads();
    float An[D_STATE], h[D_STATE], ap[D_STATE];
#pragma unroll
    for (int s = 0; s < D_STATE; ++s) {
        An[s] = -expf(A_log[d * D_STATE + s]);
        h[s] = 0.f; ap[s] = 1.f;
    }
#pragma unroll
    for (int tt = 0; tt < CHUNK; ++tt) {
        const float dt = DT[(t0 + tt) * D_INNER + d];
        const float u  = XC[(t0 + tt) * D_INNER + d];
        const float dtu = dt * u;
#pragma unroll
        for (int s = 0; s < D_STATE; ++s) {
            const float a = expf(dt * An[s]);
            h[s] = fmaf(a, h[s], dtu * Bs[tt][s]);
            ap[s] *= a;
        }
    }
    float* apd = Aprod + (chunk * D_INNER + d) * D_STATE;
    float* hpd = Hpart + (chunk * D_INNER + d) * D_STATE;
#pragma unroll
    for (int s = 0; s < D_STATE; ++s) { apd[s] = ap[s]; hpd[s] = h[s]; }
}

// ---------- phase 2 ([chunk][d*16+s], NCHUNK=256 sequential steps)
__global__ __launch_bounds__(256) void scan_phase2_k(
    const float* __restrict__ Aprod, const float* __restrict__ Hpart,
    float* __restrict__ Hinit)
{
    const int tid = blockIdx.x * 256 + threadIdx.x;
    float h = 0.f;
#pragma unroll 8
    for (int c = 0; c < NCHUNK; ++c) {
        const int idx = c * (D_INNER * D_STATE) + tid;
        Hinit[idx] = h;
        h = fmaf(Aprod[idx], h, Hpart[idx]);
    }
}

// ---------- scan phase 3: thread = one d; in-register y-reduction; fused u*D + gate
__global__ __launch_bounds__(256) void scan_phase3_k(
    const float* __restrict__ XC, const float* __restrict__ DT,
    const float* __restrict__ XDT, const float* __restrict__ G,
    const float* __restrict__ A_log, const float* __restrict__ Dp,
    const float* __restrict__ Hinit, float* __restrict__ YG)
{
    __shared__ float Bs[CHUNK][D_STATE];
    __shared__ float Cs[CHUNK][D_STATE];
    const int d = blockIdx.x * 256 + threadIdx.x;   // grid.x = 3
    const int chunk = blockIdx.y;
    const int t0 = chunk * CHUNK;
    if (threadIdx.x < CHUNK * D_STATE) {
        const int tt = threadIdx.x >> 4, s = threadIdx.x & 15;
        Bs[tt][s] = XDT[(DT_RANK + s) * NTOK + t0 + tt];
        Cs[tt][s] = XDT[(DT_RANK + D_STATE + s) * NTOK + t0 + tt];
    }
    __syncthreads();
    const float Dv = Dp[d];
    float An[D_STATE], h[D_STATE];
    const float* hin = Hinit + (chunk * D_INNER + d) * D_STATE;
#pragma unroll
    for (int s = 0; s < D_STATE; ++s) {
        An[s] = -expf(A_log[d * D_STATE + s]);
        h[s] = hin[s];
    }
#pragma unroll
    for (int tt = 0; tt < CHUNK; ++tt) {
        const float dt = DT[(t0 + tt) * D_INNER + d];
        const float u  = XC[(t0 + tt) * D_INNER + d];
        const float g  = G[(t0 + tt) * D_INNER + d];
        const float dtu = dt * u;
        float y = 0.f;
#pragma unroll
        for (int s = 0; s < D_STATE; ++s) {
            const float a = expf(dt * An[s]);
            h[s] = fmaf(a, h[s], dtu * Bs[tt][s]);
            y = fmaf(h[s], Cs[tt][s], y);
        }
        YG[(t0 + tt) * D_INNER + d] = (y + u * Dv) * g;
    }
}

extern "C" void kernel_launch(void* const* d_in, const int* in_sizes, int n_in,
                              void* d_out, int out_size, void* d_ws, size_t ws_size,
                              hipStream_t stream)
{
    const float* x        = (const float*)d_in[0];
    const float* norm_w   = (const float*)d_in[1];
    const float* in_proj  = (const float*)d_in[2];
    const float* conv_w   = (const float*)d_in[3];
    const float* conv_b   = (const float*)d_in[4];
    const float* x_proj   = (const float*)d_in[5];
    const float* dt_proj  = (const float*)d_in[6];
    const float* dt_b     = (const float*)d_in[7];
    const float* A_log    = (const float*)d_in[8];
    const float* D_param  = (const float*)d_in[9];
    const float* out_proj = (const float*)d_in[10];

    float* ws = (float*)d_ws;
    float* R     = ws;                     // 786432
    float* XP    = R   + 786432;           // 1572864 (alias: PX 917504)
    float* XnHL  = XP  + 1572864;          // 786432  (Xnh/Xnl)
    float* G     = XnHL + 786432;          // 1572864 (alias: PO after phase3)
    float* XC    = G   + 1572864;          // 1572864
    float* XDT   = XC  + 1572864;          // 114688
    float* DT    = XDT + 114688;           // 1572864
    float* YG    = DT  + 1572864;          // 1572864
    float* WS1   = YG  + 1572864;          // weight splits
    unsigned short* Xnh  = (unsigned short*)XnHL;
    unsigned short* Xnl  = Xnh + 786432;
    unsigned short* WinH = (unsigned short*)WS1;                 // 6*1536*384
    unsigned short* WinL = WinH + 6 * 1536 * 384;
    unsigned short* WoutH = WinL + 6 * 1536 * 384;               // 6*384*768
    unsigned short* WoutL = WoutH + 6 * 384 * 768;
    // dedicated scan state buffers (NCHUNK*768*16 = 3,145,728 floats = 12.6 MB each)
    float* SCAN  = (float*)(WoutL + 6 * 384 * 768);
    float* Aprod = SCAN;
    float* Hpart = Aprod + (size_t)NCHUNK * D_INNER * D_STATE;
    float* Hinit = Hpart + (size_t)NCHUNK * D_INNER * D_STATE;
    float* PX    = XP;
    float* PO    = G;

    hipMemcpyAsync(R, x, (size_t)786432 * sizeof(float), hipMemcpyDeviceToDevice, stream);

    // pre-split weights (once per launch, identical work every call)
    presplit_k<<<(6 * 1536 * 384 / 4 + 255) / 256, 256, 0, stream>>>(
        in_proj, WinH, WinL, 6 * 1536 * 384 / 4);
    presplit_k<<<(6 * 384 * 768 / 4 + 255) / 256, 256, 0, stream>>>(
        out_proj, WoutH, WoutL, 6 * 384 * 768 / 4);

    for (int b = 0; b < 6; ++b) {
        rmsnorm_gather_k<<<NTOK, 128, 0, stream>>>(R, norm_w + b * D_MODEL, Xnh, Xnl, b);

        inproj_mfma_k<<<dim3(24, 32), 256, 0, stream>>>(
            Xnh, Xnl, WinH + (size_t)b * 1536 * 384, WinL + (size_t)b * 1536 * 384, XP, G);

        conv_silu_k<<<dim3(3, NTOK), 256, 0, stream>>>(
            XP, conv_w + b * D_INNER * 4, conv_b + b * D_INNER, XC);

        // x_proj split-K: XC(2048x768 row-major) x W(56x768)^T -> PX[z][e][t]
        gemm_k<3, false><<<dim3(1, 32, 8), 256, 0, stream>>>(
            XC, D_INNER, x_proj + (size_t)b * XDIM * D_INNER, PX,
            NTOK, XDIM, D_INNER, nullptr, nullptr, 96);

        reduce_px_k<<<112, 256, 0, stream>>>(PX, XDT);

        // dt_proj: (XDT rows 0..23)^T x W(768x24)^T -> DT[t][d] softplus+bias
        gemm_k<1, true><<<dim3(12, 32, 1), 256, 0, stream>>>(
            XDT, NTOK, dt_proj + (size_t)b * D_INNER * DT_RANK, DT,
            NTOK, D_INNER, DT_RANK, dt_b + b * D_INNER, nullptr, DT_RANK);

        scan_phase1_k<<<dim3(3, NCHUNK), 256, 0, stream>>>(
            XC, DT, XDT, A_log + (size_t)b * D_INNER * D_STATE, Aprod, Hpart);

        scan_phase2_k<<<48, 256, 0, stream>>>(Aprod, Hpart, Hinit);

        scan_phase3_k<<<dim3(3, NCHUNK), 256, 0, stream>>>(
            XC, DT, XDT, G, A_log + (size_t)b * D_INNER * D_STATE,
            D_param + b * D_INNER, Hinit, YG);

        outproj_mfma_k<<<dim3(6, 32, 2), 256, 0, stream>>>(
            YG, WoutH + (size_t)b * 384 * 768, WoutL + (size_t)b * 384 * 768, PO);

        reduce_scatter_k<<<NTOK, 384, 0, stream>>>(PO, R, b);
    }

    hipMemcpyAsync(d_out, R, (size_t)786432 * sizeof(float), hipMemcpyDeviceToDevice, stream);
}